// Round 2
// baseline (2714.628 us; speedup 1.0000x reference)
//
#include <hip/hip_runtime.h>
#include <math.h>

// Problem constants
#define NB 1024    // batch
#define NAG 64     // agents
#define OBS 128
#define ACTD 16
#define HID 256
#define GD 64
#define NH 4       // heads

// ---------------- row softmax (for causal_structure / scm_causal) ----------------
__global__ __launch_bounds__(64) void softmax_rows_k(const float* __restrict__ in,
                                                     float* __restrict__ out, int n) {
  int row = blockIdx.x;
  int lane = threadIdx.x;
  const float* r = in + (size_t)row * n;
  float m = -INFINITY;
  for (int j = lane; j < n; j += 64) m = fmaxf(m, r[j]);
#pragma unroll
  for (int off = 32; off; off >>= 1) m = fmaxf(m, __shfl_xor(m, off));
  float s = 0.f;
  for (int j = lane; j < n; j += 64) s += expf(r[j] - m);
#pragma unroll
  for (int off = 32; off; off >>= 1) s += __shfl_xor(s, off);
  float inv = 1.f / s;
  for (int j = lane; j < n; j += 64) out[(size_t)row * n + j] = expf(r[j] - m) * inv;
}

// ---------------- repack W (H,F,D) -> Wc (F, H*D) ----------------
__global__ void repack_w_k(const float* __restrict__ W, float* __restrict__ Wc, int F) {
  int idx = blockIdx.x * 256 + threadIdx.x;
  int total = NH * F * GD;
  if (idx >= total) return;
  int d = idx & 63;
  int f = (idx >> 6) % F;
  int h = idx / (F * 64);
  Wc[(size_t)f * (NH * GD) + h * GD + d] = W[idx];
}

// ---------------- generic tiled fp32 GEMM ----------------
// C = act(A @ B + bias); A (M,K) row stride lda; B (K,N) row-major; C row stride ldc.
// blockIdx.z = batch (agent) with per-batch element offsets aBS/bBS/biasBS/cBS,
// OR K-split slice when kPerSplit>0 (then only cBS applies).
__global__ __launch_bounds__(256) void gemm_k(
    const float* __restrict__ A, const float* __restrict__ Bm,
    const float* __restrict__ bias, float* __restrict__ C,
    int M, int N, int K,
    long long lda, long long ldc,
    long long aBS, long long bBS, long long biasBS, long long cBS,
    int act, int kPerSplit) {
  __shared__ float As[16][64];  // transposed: As[k][m]
  __shared__ float Bs[16][64];
  int tid = threadIdx.x;
  int tx = tid & 15, ty = tid >> 4;
  int m0 = blockIdx.x * 64, n0 = blockIdx.y * 64;
  int z = blockIdx.z;
  const float* Ab;
  const float* Bb;
  const float* biasb = nullptr;
  float* Cb;
  int k_begin, k_end;
  if (kPerSplit > 0) {
    Ab = A; Bb = Bm; Cb = C + (long long)z * cBS;
    k_begin = z * kPerSplit;
    k_end = k_begin + kPerSplit;
    if (k_end > K) k_end = K;
  } else {
    Ab = A + (long long)z * aBS;
    Bb = Bm + (long long)z * bBS;
    if (bias) biasb = bias + (long long)z * biasBS;
    Cb = C + (long long)z * cBS;
    k_begin = 0; k_end = K;
  }
  float acc[4][4] = {};
  int arow = tid >> 2;        // 0..63
  int ak = (tid & 3) * 4;     // 0,4,8,12
  int bk = tid >> 4;          // 0..15
  int bn = (tid & 15) * 4;    // 0..60
  for (int k0 = k_begin; k0 < k_end; k0 += 16) {
    float4 av = *(const float4*)(Ab + (long long)(m0 + arow) * lda + (k0 + ak));
    As[ak + 0][arow] = av.x;
    As[ak + 1][arow] = av.y;
    As[ak + 2][arow] = av.z;
    As[ak + 3][arow] = av.w;
    const float* bp = Bb + (long long)(k0 + bk) * N + n0;
#pragma unroll
    for (int j = 0; j < 4; ++j) {
      int n = bn + j;
      Bs[bk][n] = (n0 + n < N) ? bp[n] : 0.f;
    }
    __syncthreads();
#pragma unroll
    for (int k = 0; k < 16; ++k) {
      float4 a4 = *(const float4*)&As[k][ty * 4];
      float4 b4 = *(const float4*)&Bs[k][tx * 4];
      float ar[4] = {a4.x, a4.y, a4.z, a4.w};
      float br[4] = {b4.x, b4.y, b4.z, b4.w};
#pragma unroll
      for (int i = 0; i < 4; ++i)
#pragma unroll
        for (int j = 0; j < 4; ++j) acc[i][j] += ar[i] * br[j];
    }
    __syncthreads();
  }
#pragma unroll
  for (int i = 0; i < 4; ++i) {
    int m = m0 + ty * 4 + i;
#pragma unroll
    for (int j = 0; j < 4; ++j) {
      int n = n0 + tx * 4 + j;
      if (n < N) {
        float v = acc[i][j];
        if (biasb) v += biasb[n];
        if (act == 1) v = fmaxf(v, 0.f);
        Cb[(long long)m * ldc + n] = v;
      }
    }
  }
}

// ---------------- GAT attention, concat output (+optional ELU), per (head,batch) ----------------
// xt layout: (B*N, NH*GD); out same layout.
__global__ __launch_bounds__(64) void gat_attn_k(
    const float* __restrict__ xt, const float* __restrict__ a,
    const float* __restrict__ adj, float* __restrict__ out, int elu) {
  int h = blockIdx.x;
  int b = blockIdx.y;
  int lane = threadIdx.x;
  __shared__ float xs[64][65];
  __shared__ float si[64], sj[64], wrow[64];
  const float4* xr4 = (const float4*)(xt + ((size_t)(b * 64 + lane)) * 256 + h * 64);
  const float* ah = a + h * 128;
  float s1 = 0.f, s2 = 0.f;
#pragma unroll
  for (int q = 0; q < 16; ++q) {
    float4 v = xr4[q];
    xs[lane][4 * q + 0] = v.x;
    xs[lane][4 * q + 1] = v.y;
    xs[lane][4 * q + 2] = v.z;
    xs[lane][4 * q + 3] = v.w;
    s1 += v.x * ah[4 * q] + v.y * ah[4 * q + 1] + v.z * ah[4 * q + 2] + v.w * ah[4 * q + 3];
    s2 += v.x * ah[64 + 4 * q] + v.y * ah[64 + 4 * q + 1] + v.z * ah[64 + 4 * q + 2] +
          v.w * ah[64 + 4 * q + 3];
  }
  si[lane] = s1;
  sj[lane] = s2;
  __syncthreads();
  const float* adjb = adj + (size_t)b * 64 * 64;
  for (int i = 0; i < 64; ++i) {
    float e = si[i] + sj[lane];
    e = e > 0.f ? e : 0.2f * e;           // leaky_relu(0.2)
    if (adjb[i * 64 + lane] == 0.f) e = -INFINITY;
    float mx = e;
#pragma unroll
    for (int off = 32; off; off >>= 1) mx = fmaxf(mx, __shfl_xor(mx, off));
    float p = (e == -INFINITY) ? 0.f : expf(e - mx);
    float sm = p;
#pragma unroll
    for (int off = 32; off; off >>= 1) sm += __shfl_xor(sm, off);
    float w = (sm > 0.f) ? p / sm : 0.f;
    wrow[lane] = w;
    __syncthreads();
    float acc = 0.f;
    for (int j = 0; j < 64; ++j) acc += wrow[j] * xs[j][lane];
    if (elu) acc = acc > 0.f ? acc : expf(acc) - 1.f;
    out[((size_t)(b * 64 + i)) * 256 + h * 64 + lane] = acc;
    __syncthreads();
  }
}

// ---------------- GAT attention, head-MEAN accumulated into comm (B,N,64) ----------------
// Loops all 4 heads per graph b; comm = 0.25*sum_h att  (add=0 init, add=1 accumulate)
__global__ __launch_bounds__(64) void gat_attn_mean_k(
    const float* __restrict__ xt, const float* __restrict__ a,
    const float* __restrict__ adj, float* __restrict__ comm, int add) {
  int b = blockIdx.x;
  int lane = threadIdx.x;
  __shared__ float xs[64][65];
  __shared__ float accs[64][65];
  __shared__ float si[64], sj[64], wrow[64];
  const float* adjb = adj + (size_t)b * 64 * 64;
  for (int h = 0; h < 4; ++h) {
    const float4* xr4 = (const float4*)(xt + ((size_t)(b * 64 + lane)) * 256 + h * 64);
    const float* ah = a + h * 128;
    float s1 = 0.f, s2 = 0.f;
#pragma unroll
    for (int q = 0; q < 16; ++q) {
      float4 v = xr4[q];
      xs[lane][4 * q + 0] = v.x;
      xs[lane][4 * q + 1] = v.y;
      xs[lane][4 * q + 2] = v.z;
      xs[lane][4 * q + 3] = v.w;
      s1 += v.x * ah[4 * q] + v.y * ah[4 * q + 1] + v.z * ah[4 * q + 2] + v.w * ah[4 * q + 3];
      s2 += v.x * ah[64 + 4 * q] + v.y * ah[64 + 4 * q + 1] + v.z * ah[64 + 4 * q + 2] +
            v.w * ah[64 + 4 * q + 3];
    }
    si[lane] = s1;
    sj[lane] = s2;
    __syncthreads();
    for (int i = 0; i < 64; ++i) {
      float e = si[i] + sj[lane];
      e = e > 0.f ? e : 0.2f * e;
      if (adjb[i * 64 + lane] == 0.f) e = -INFINITY;
      float mx = e;
#pragma unroll
      for (int off = 32; off; off >>= 1) mx = fmaxf(mx, __shfl_xor(mx, off));
      float p = (e == -INFINITY) ? 0.f : expf(e - mx);
      float sm = p;
#pragma unroll
      for (int off = 32; off; off >>= 1) sm += __shfl_xor(sm, off);
      float w = (sm > 0.f) ? p / sm : 0.f;
      wrow[lane] = w;
      __syncthreads();
      float d = 0.f;
      for (int j = 0; j < 64; ++j) d += wrow[j] * xs[j][lane];
      if (h == 0) accs[i][lane] = 0.25f * d;
      else accs[i][lane] += 0.25f * d;
      __syncthreads();
    }
  }
  float* cb = comm + (size_t)b * 64 * 64;
  for (int i = 0; i < 64; ++i) {
    float v = accs[i][lane];
    cb[i * 64 + lane] = add ? (cb[i * 64 + lane] + v) : v;
  }
}

// ---------------- ai = [obs, comm] (B,N,192) ----------------
__global__ void build_ai_k(const float* __restrict__ obs, const float* __restrict__ comm,
                           float* __restrict__ ai) {
  size_t idx = (size_t)blockIdx.x * 256 + threadIdx.x;
  if (idx >= (size_t)NB * NAG * 192) return;
  int c = (int)(idx % 192);
  size_t bn = idx / 192;
  ai[idx] = (c < 128) ? obs[bn * 128 + c] : comm[bn * 64 + (c - 128)];
}

// ---------------- combined = [obs, actions] (B,N,144) ----------------
__global__ void build_combined_k(const float* __restrict__ obs, const float* __restrict__ act,
                                 float* __restrict__ cmb) {
  size_t idx = (size_t)blockIdx.x * 256 + threadIdx.x;
  if (idx >= (size_t)NB * NAG * 144) return;
  int c = (int)(idx % 144);
  size_t bn = idx / 144;
  cmb[idx] = (c < 128) ? obs[bn * 128 + c] : act[bn * 16 + (c - 128)];
}

// ---------------- split-K reduce + bias + relu for cent l1 ----------------
__global__ void reduce_bias_relu_k(const float* __restrict__ part, const float* __restrict__ bias,
                                   float* __restrict__ out) {
  int idx = blockIdx.x * 256 + threadIdx.x;  // 1024*256
  float s = 0.f;
#pragma unroll
  for (int zz = 0; zz < 16; ++zz) s += part[(size_t)zz * 262144 + idx];
  s += bias[idx & 255];
  out[idx] = fmaxf(s, 0.f);
}

// ---------------- scm_pred = cw @ ce + noise ----------------
__global__ __launch_bounds__(256) void se_noise_k(const float* __restrict__ cw,
                                                  const float* __restrict__ ce,
                                                  const float* __restrict__ nz,
                                                  float* __restrict__ out) {
  int b = blockIdx.x;
  __shared__ float ceL[64 * 128];
  __shared__ float cwL[64 * 64];
  const float* cb = ce + (size_t)b * 8192;
  for (int idx = threadIdx.x; idx < 8192; idx += 256) ceL[idx] = cb[idx];
  for (int idx = threadIdx.x; idx < 4096; idx += 256) cwL[idx] = cw[idx];
  __syncthreads();
  for (int idx = threadIdx.x; idx < 8192; idx += 256) {
    int i = idx >> 7, d = idx & 127;
    float acc = 0.f;
    for (int j = 0; j < 64; ++j) acc += cwL[i * 64 + j] * ceL[j * 128 + d];
    out[(size_t)b * 8192 + idx] = acc + nz[(size_t)b * 8192 + idx];
  }
}

extern "C" void kernel_launch(void* const* d_in, const int* in_sizes, int n_in,
                              void* d_out, int out_size, void* d_ws, size_t ws_size,
                              hipStream_t stream) {
  (void)in_sizes; (void)n_in; (void)out_size; (void)ws_size;
  const float* obs = (const float*)d_in[0];
  const float* acts = (const float*)d_in[1];
  const float* adj = (const float*)d_in[2];
  const float* causal = (const float*)d_in[3];
  const float* gat_W = (const float*)d_in[4];
  const float* gat_a = (const float*)d_in[5];
  const float* cg_W0 = (const float*)d_in[6];
  const float* cg_a0 = (const float*)d_in[7];
  const float* cg_W1 = (const float*)d_in[8];
  const float* cg_a1 = (const float*)d_in[9];
  const float* aw1 = (const float*)d_in[10]; const float* ab1 = (const float*)d_in[11];
  const float* aw2 = (const float*)d_in[12]; const float* ab2 = (const float*)d_in[13];
  const float* aw3 = (const float*)d_in[14]; const float* ab3 = (const float*)d_in[15];
  const float* crw1 = (const float*)d_in[16]; const float* crb1 = (const float*)d_in[17];
  const float* crw2 = (const float*)d_in[18]; const float* crb2 = (const float*)d_in[19];
  const float* crw3 = (const float*)d_in[20]; const float* crb3 = (const float*)d_in[21];
  const float* cew1 = (const float*)d_in[22]; const float* ceb1 = (const float*)d_in[23];
  const float* cew2 = (const float*)d_in[24]; const float* ceb2 = (const float*)d_in[25];
  const float* cew3 = (const float*)d_in[26]; const float* ceb3 = (const float*)d_in[27];
  const float* scm_causal = (const float*)d_in[28];
  const float* mw1 = (const float*)d_in[29]; const float* mb1 = (const float*)d_in[30];
  const float* mw2 = (const float*)d_in[31]; const float* mb2 = (const float*)d_in[32];
  const float* mw3 = (const float*)d_in[33]; const float* mb3 = (const float*)d_in[34];
  const float* nw1 = (const float*)d_in[35]; const float* nb1 = (const float*)d_in[36];
  const float* nw2 = (const float*)d_in[37]; const float* nb2 = (const float*)d_in[38];

  // workspace layout (floats) — total 50,417,664 floats = 192.3 MiB
  float* ws = (float*)d_ws;
  float* Ssm  = ws;               // 16384
  float* cwsm = ws + 16384;       // 4096
  float* wc   = ws + 20480;       // 65536 (reused for all 3 GAT weight repacks)
  float* comm = ws + 86016;       // 4,194,304  (B,N,64)
  float* AI   = ws + 4280320;     // 12,582,912 (B,N,192): ai -> combined -> ce
  float* H1   = ws + 16863232;    // 16,777,216 (B,N,256): xt -> h1 -> partials/h2c
  float* HCG  = ws + 33640448;    // 16,777,216 (B,N,256): xm -> hcg -> h2 -> h1c -> noise

  float* out_actor = (float*)d_out;
  float* out_critic = out_actor + 1048576;
  float* out_cent = out_critic + 65536;
  float* out_scm = out_cent + 65536;

  auto GEMM = [&](const float* A, const float* Bm, const float* bias, float* C,
                  int M, int N, int K, long long lda, long long ldc,
                  long long aBS, long long bBS, long long biasBS, long long cBS,
                  int act, int gz, int kPerSplit) {
    dim3 grid(M / 64, (N + 63) / 64, gz);
    hipLaunchKernelGGL(gemm_k, grid, dim3(256), 0, stream, A, Bm, bias, C, M, N, K,
                       lda, ldc, aBS, bBS, biasBS, cBS, act, kPerSplit);
  };

  // 0) small softmaxes
  hipLaunchKernelGGL(softmax_rows_k, dim3(128), dim3(64), 0, stream, causal, Ssm, 128);
  hipLaunchKernelGGL(softmax_rows_k, dim3(64), dim3(64), 0, stream, scm_causal, cwsm, 64);

  // 1) plain GAT -> comm (init)
  hipLaunchKernelGGL(repack_w_k, dim3((NH * 128 * 64 + 255) / 256), dim3(256), 0, stream, gat_W, wc, 128);
  GEMM(obs, wc, nullptr, H1, 65536, 256, 128, 128, 256, 0, 0, 0, 0, 0, 1, 0);        // xt1
  hipLaunchKernelGGL(gat_attn_mean_k, dim3(1024), dim3(64), 0, stream, H1, gat_a, adj, comm, 0);

  // 2) causal GAT
  GEMM(obs, Ssm, nullptr, HCG, 65536, 128, 128, 128, 128, 0, 0, 0, 0, 0, 1, 0);      // xm
  hipLaunchKernelGGL(repack_w_k, dim3((NH * 128 * 64 + 255) / 256), dim3(256), 0, stream, cg_W0, wc, 128);
  GEMM(HCG, wc, nullptr, H1, 65536, 256, 128, 128, 256, 0, 0, 0, 0, 0, 1, 0);        // xt_cg0
  hipLaunchKernelGGL(gat_attn_k, dim3(4, 1024), dim3(64), 0, stream, H1, cg_a0, adj, HCG, 1); // hcg (ELU)
  hipLaunchKernelGGL(repack_w_k, dim3((NH * 256 * 64 + 255) / 256), dim3(256), 0, stream, cg_W1, wc, 256);
  GEMM(HCG, wc, nullptr, H1, 65536, 256, 256, 256, 256, 0, 0, 0, 0, 0, 1, 0);        // xt_cg1
  hipLaunchKernelGGL(gat_attn_mean_k, dim3(1024), dim3(64), 0, stream, H1, cg_a1, adj, comm, 1);

  // 3) ai = [obs, comm]
  hipLaunchKernelGGL(build_ai_k, dim3((12582912 + 255) / 256), dim3(256), 0, stream, obs, comm, AI);

  // 4) actor MLP (per-agent)
  GEMM(AI, aw1, ab1, H1, 1024, 256, 192, 12288, 16384, 192, 49152, 256, 256, 1, 64, 0);
  GEMM(H1, aw2, ab2, HCG, 1024, 256, 256, 16384, 16384, 256, 65536, 256, 256, 1, 64, 0);
  GEMM(HCG, aw3, ab3, out_actor, 1024, 16, 256, 16384, 1024, 256, 4096, 16, 16, 0, 64, 0);

  // 5) critic MLP (per-agent)
  GEMM(AI, crw1, crb1, H1, 1024, 256, 192, 12288, 16384, 192, 49152, 256, 256, 1, 64, 0);
  GEMM(H1, crw2, crb2, HCG, 1024, 256, 256, 16384, 16384, 256, 65536, 256, 256, 1, 64, 0);
  GEMM(HCG, crw3, crb3, out_critic, 1024, 1, 256, 16384, 64, 256, 256, 1, 1, 0, 64, 0);

  // 6) centralized critic (combined -> AI; ai no longer needed)
  hipLaunchKernelGGL(build_combined_k, dim3((9437184 + 255) / 256), dim3(256), 0, stream, obs, acts, AI);
  GEMM(AI, cew1, nullptr, H1, 1024, 256, 9216, 9216, 256, 0, 0, 0, 262144, 0, 16, 576); // partials
  hipLaunchKernelGGL(reduce_bias_relu_k, dim3(1024), dim3(256), 0, stream, H1, ceb1, HCG);
  GEMM(HCG, cew2, ceb2, H1, 1024, 256, 256, 256, 256, 0, 0, 0, 0, 1, 1, 0);
  GEMM(H1, cew3, ceb3, out_cent, 1024, 64, 256, 256, 64, 0, 0, 0, 0, 0, 1, 0);

  // 7) SCM mechanisms (input = combined in AI)
  GEMM(AI, mw1, mb1, H1, 1024, 256, 144, 9216, 16384, 144, 36864, 256, 256, 1, 64, 0);
  GEMM(H1, mw2, mb2, HCG, 1024, 256, 256, 16384, 16384, 256, 65536, 256, 256, 1, 64, 0);
  GEMM(HCG, mw3, mb3, AI, 1024, 128, 256, 16384, 8192, 256, 32768, 128, 128, 0, 64, 0); // ce -> AI

  // 8) noise model (input = obs)
  GEMM(obs, nw1, nb1, H1, 1024, 256, 128, 8192, 16384, 128, 32768, 256, 256, 1, 64, 0);
  GEMM(H1, nw2, nb2, HCG, 1024, 128, 256, 16384, 8192, 256, 32768, 128, 128, 0, 64, 0); // noise -> HCG

  // 9) scm_pred = softmax(scm_causal) @ ce + noise
  hipLaunchKernelGGL(se_noise_k, dim3(1024), dim3(256), 0, stream, cwsm, AI, HCG, out_scm);
}

// Round 3
// 2074.808 us; speedup vs baseline: 1.3084x; 1.3084x over previous
//
#include <hip/hip_runtime.h>
#include <math.h>

// Problem constants
#define NB 1024    // batch
#define NAG 64     // agents
#define OBS 128
#define ACTD 16
#define HID 256
#define GD 64
#define NH 4       // heads

// ---------------- row softmax (for causal_structure / scm_causal) ----------------
__global__ __launch_bounds__(64) void softmax_rows_k(const float* __restrict__ in,
                                                     float* __restrict__ out, int n) {
  int row = blockIdx.x;
  int lane = threadIdx.x;
  const float* r = in + (size_t)row * n;
  float m = -INFINITY;
  for (int j = lane; j < n; j += 64) m = fmaxf(m, r[j]);
#pragma unroll
  for (int off = 32; off; off >>= 1) m = fmaxf(m, __shfl_xor(m, off));
  float s = 0.f;
  for (int j = lane; j < n; j += 64) s += expf(r[j] - m);
#pragma unroll
  for (int off = 32; off; off >>= 1) s += __shfl_xor(s, off);
  float inv = 1.f / s;
  for (int j = lane; j < n; j += 64) out[(size_t)row * n + j] = expf(r[j] - m) * inv;
}

// ---------------- repack W (H,F,D) -> Wc (F, H*D) ----------------
__global__ void repack_w_k(const float* __restrict__ W, float* __restrict__ Wc, int F) {
  int idx = blockIdx.x * 256 + threadIdx.x;
  int total = NH * F * GD;
  if (idx >= total) return;
  int d = idx & 63;
  int f = (idx >> 6) % F;
  int h = idx / (F * 64);
  Wc[(size_t)f * (NH * GD) + h * GD + d] = W[idx];
}

// ---------------- generic tiled fp32 GEMM ----------------
__global__ __launch_bounds__(256) void gemm_k(
    const float* __restrict__ A, const float* __restrict__ Bm,
    const float* __restrict__ bias, float* __restrict__ C,
    int M, int N, int K,
    long long lda, long long ldc,
    long long aBS, long long bBS, long long biasBS, long long cBS,
    int act, int kPerSplit) {
  __shared__ float As[16][64];  // transposed: As[k][m]
  __shared__ float Bs[16][64];
  int tid = threadIdx.x;
  int tx = tid & 15, ty = tid >> 4;
  int m0 = blockIdx.x * 64, n0 = blockIdx.y * 64;
  int z = blockIdx.z;
  const float* Ab;
  const float* Bb;
  const float* biasb = nullptr;
  float* Cb;
  int k_begin, k_end;
  if (kPerSplit > 0) {
    Ab = A; Bb = Bm; Cb = C + (long long)z * cBS;
    k_begin = z * kPerSplit;
    k_end = k_begin + kPerSplit;
    if (k_end > K) k_end = K;
  } else {
    Ab = A + (long long)z * aBS;
    Bb = Bm + (long long)z * bBS;
    if (bias) biasb = bias + (long long)z * biasBS;
    Cb = C + (long long)z * cBS;
    k_begin = 0; k_end = K;
  }
  float acc[4][4] = {};
  int arow = tid >> 2;
  int ak = (tid & 3) * 4;
  int bk = tid >> 4;
  int bn = (tid & 15) * 4;
  for (int k0 = k_begin; k0 < k_end; k0 += 16) {
    float4 av = *(const float4*)(Ab + (long long)(m0 + arow) * lda + (k0 + ak));
    As[ak + 0][arow] = av.x;
    As[ak + 1][arow] = av.y;
    As[ak + 2][arow] = av.z;
    As[ak + 3][arow] = av.w;
    const float* bp = Bb + (long long)(k0 + bk) * N + n0;
#pragma unroll
    for (int j = 0; j < 4; ++j) {
      int n = bn + j;
      Bs[bk][n] = (n0 + n < N) ? bp[n] : 0.f;
    }
    __syncthreads();
#pragma unroll
    for (int k = 0; k < 16; ++k) {
      float4 a4 = *(const float4*)&As[k][ty * 4];
      float4 b4 = *(const float4*)&Bs[k][tx * 4];
      float ar[4] = {a4.x, a4.y, a4.z, a4.w};
      float br[4] = {b4.x, b4.y, b4.z, b4.w};
#pragma unroll
      for (int i = 0; i < 4; ++i)
#pragma unroll
        for (int j = 0; j < 4; ++j) acc[i][j] += ar[i] * br[j];
    }
    __syncthreads();
  }
#pragma unroll
  for (int i = 0; i < 4; ++i) {
    int m = m0 + ty * 4 + i;
#pragma unroll
    for (int j = 0; j < 4; ++j) {
      int n = n0 + tx * 4 + j;
      if (n < N) {
        float v = acc[i][j];
        if (biasb) v += biasb[n];
        if (act == 1) v = fmaxf(v, 0.f);
        Cb[(long long)m * ldc + n] = v;
      }
    }
  }
}

// ---------------- GAT attention, 4 waves per graph, head loop inside ----------------
// xt layout: (B*N, NH*GD). mode: 0 = comm  = 0.25*sum_h att
//                           1 = comm += 0.25*sum_h att
//                           2 = out(concat) = elu(att)   [out is (B*N, NH*GD)]
__global__ __launch_bounds__(256) void gat_attn4_k(
    const float* __restrict__ xt, const float* __restrict__ a,
    const float* __restrict__ adj, float* __restrict__ out, int mode) {
  int b = blockIdx.x;
  int tid = threadIdx.x;
  int wave = tid >> 6, lane = tid & 63;
  __shared__ float xs[64][68];    // [j][d]
  __shared__ float wsT[64][68];   // [j][i]  (transposed scores)
  __shared__ float si[64], sj[64];

  // preload this wave's 16 adjacency rows (i = wave*16+r)
  const float* adjb = adj + (size_t)b * 4096;
  float adjv[16];
#pragma unroll
  for (int r = 0; r < 16; ++r) adjv[r] = adjb[(size_t)(wave * 16 + r) * 64 + lane];

  float accm[16];
  int lrow = tid >> 2;      // load-phase row 0..63 (wave w -> rows 16w..16w+15)
  int cg = tid & 3;         // 16-col group

  for (int h = 0; h < 4; ++h) {
    // ---- load xs + si/sj partial dots
    const float* xrow = xt + ((size_t)(b * 64 + lrow)) * 256 + h * 64 + cg * 16;
    const float* ah = a + h * 128;
    float p1 = 0.f, p2 = 0.f;
#pragma unroll
    for (int q = 0; q < 4; ++q) {
      float4 v = *(const float4*)(xrow + 4 * q);
      int c = cg * 16 + 4 * q;
      xs[lrow][c + 0] = v.x; xs[lrow][c + 1] = v.y;
      xs[lrow][c + 2] = v.z; xs[lrow][c + 3] = v.w;
      p1 += v.x * ah[c] + v.y * ah[c + 1] + v.z * ah[c + 2] + v.w * ah[c + 3];
      p2 += v.x * ah[64 + c] + v.y * ah[64 + c + 1] + v.z * ah[64 + c + 2] + v.w * ah[64 + c + 3];
    }
    p1 += __shfl_xor(p1, 1); p1 += __shfl_xor(p1, 2);
    p2 += __shfl_xor(p2, 1); p2 += __shfl_xor(p2, 2);
    if (cg == 0) { si[lrow] = p1; sj[lrow] = p2; }
    __syncthreads();

    // ---- scores + row softmax; wave owns rows i = wave*16+r, lane = j
#pragma unroll
    for (int r = 0; r < 16; ++r) {
      int i = wave * 16 + r;
      float e = si[i] + sj[lane];
      e = e > 0.f ? e : 0.2f * e;              // leaky_relu(0.2)
      if (adjv[r] == 0.f) e = -INFINITY;
      float mx = e;
#pragma unroll
      for (int off = 32; off; off >>= 1) mx = fmaxf(mx, __shfl_xor(mx, off));
      float p = (e == -INFINITY) ? 0.f : expf(e - mx);
      float sm = p;
#pragma unroll
      for (int off = 32; off; off >>= 1) sm += __shfl_xor(sm, off);
      wsT[lane][i] = (sm > 0.f) ? p / sm : 0.f;
    }
    // no barrier needed: this wave reads only the wsT columns it just wrote

    // ---- PV: lane = feature d; acc[r] over j
    float acc[16];
#pragma unroll
    for (int r = 0; r < 16; ++r) acc[r] = 0.f;
    for (int j = 0; j < 64; ++j) {
      float xv = xs[j][lane];
#pragma unroll
      for (int r4 = 0; r4 < 4; ++r4) {
        float4 w4 = *(const float4*)&wsT[j][wave * 16 + r4 * 4];
        acc[r4 * 4 + 0] += w4.x * xv;
        acc[r4 * 4 + 1] += w4.y * xv;
        acc[r4 * 4 + 2] += w4.z * xv;
        acc[r4 * 4 + 3] += w4.w * xv;
      }
    }
    if (mode == 2) {
#pragma unroll
      for (int r = 0; r < 16; ++r) {
        int i = wave * 16 + r;
        float v = acc[r];
        v = v > 0.f ? v : expf(v) - 1.f;       // ELU
        out[((size_t)(b * 64 + i)) * 256 + h * 64 + lane] = v;
      }
    } else {
#pragma unroll
      for (int r = 0; r < 16; ++r) {
        if (h == 0) accm[r] = 0.25f * acc[r];
        else accm[r] += 0.25f * acc[r];
      }
    }
    __syncthreads();  // protect xs/si/sj before next head's load
  }

  if (mode != 2) {
    float* cb = out + (size_t)b * 4096;
#pragma unroll
    for (int r = 0; r < 16; ++r) {
      int i = wave * 16 + r;
      if (mode == 1) cb[i * 64 + lane] += accm[r];
      else cb[i * 64 + lane] = accm[r];
    }
  }
}

// ---------------- ai = [obs, comm] (B,N,192) ----------------
__global__ void build_ai_k(const float* __restrict__ obs, const float* __restrict__ comm,
                           float* __restrict__ ai) {
  size_t idx = (size_t)blockIdx.x * 256 + threadIdx.x;
  if (idx >= (size_t)NB * NAG * 192) return;
  int c = (int)(idx % 192);
  size_t bn = idx / 192;
  ai[idx] = (c < 128) ? obs[bn * 128 + c] : comm[bn * 64 + (c - 128)];
}

// ---------------- combined = [obs, actions] (B,N,144) ----------------
__global__ void build_combined_k(const float* __restrict__ obs, const float* __restrict__ act,
                                 float* __restrict__ cmb) {
  size_t idx = (size_t)blockIdx.x * 256 + threadIdx.x;
  if (idx >= (size_t)NB * NAG * 144) return;
  int c = (int)(idx % 144);
  size_t bn = idx / 144;
  cmb[idx] = (c < 128) ? obs[bn * 128 + c] : act[bn * 16 + (c - 128)];
}

// ---------------- split-K reduce + bias + relu for cent l1 ----------------
__global__ void reduce_bias_relu_k(const float* __restrict__ part, const float* __restrict__ bias,
                                   float* __restrict__ out) {
  int idx = blockIdx.x * 256 + threadIdx.x;  // 1024*256
  float s = 0.f;
#pragma unroll
  for (int zz = 0; zz < 16; ++zz) s += part[(size_t)zz * 262144 + idx];
  s += bias[idx & 255];
  out[idx] = fmaxf(s, 0.f);
}

// ---------------- scm_pred = cw @ ce + noise ----------------
__global__ __launch_bounds__(256) void se_noise_k(const float* __restrict__ cw,
                                                  const float* __restrict__ ce,
                                                  const float* __restrict__ nz,
                                                  float* __restrict__ out) {
  int b = blockIdx.x;
  __shared__ float ceL[64 * 128];
  __shared__ float cwL[64 * 64];
  const float* cb = ce + (size_t)b * 8192;
  for (int idx = threadIdx.x; idx < 8192; idx += 256) ceL[idx] = cb[idx];
  for (int idx = threadIdx.x; idx < 4096; idx += 256) cwL[idx] = cw[idx];
  __syncthreads();
  for (int idx = threadIdx.x; idx < 8192; idx += 256) {
    int i = idx >> 7, d = idx & 127;
    float acc = 0.f;
    for (int j = 0; j < 64; ++j) acc += cwL[i * 64 + j] * ceL[j * 128 + d];
    out[(size_t)b * 8192 + idx] = acc + nz[(size_t)b * 8192 + idx];
  }
}

extern "C" void kernel_launch(void* const* d_in, const int* in_sizes, int n_in,
                              void* d_out, int out_size, void* d_ws, size_t ws_size,
                              hipStream_t stream) {
  (void)in_sizes; (void)n_in; (void)out_size; (void)ws_size;
  const float* obs = (const float*)d_in[0];
  const float* acts = (const float*)d_in[1];
  const float* adj = (const float*)d_in[2];
  const float* causal = (const float*)d_in[3];
  const float* gat_W = (const float*)d_in[4];
  const float* gat_a = (const float*)d_in[5];
  const float* cg_W0 = (const float*)d_in[6];
  const float* cg_a0 = (const float*)d_in[7];
  const float* cg_W1 = (const float*)d_in[8];
  const float* cg_a1 = (const float*)d_in[9];
  const float* aw1 = (const float*)d_in[10]; const float* ab1 = (const float*)d_in[11];
  const float* aw2 = (const float*)d_in[12]; const float* ab2 = (const float*)d_in[13];
  const float* aw3 = (const float*)d_in[14]; const float* ab3 = (const float*)d_in[15];
  const float* crw1 = (const float*)d_in[16]; const float* crb1 = (const float*)d_in[17];
  const float* crw2 = (const float*)d_in[18]; const float* crb2 = (const float*)d_in[19];
  const float* crw3 = (const float*)d_in[20]; const float* crb3 = (const float*)d_in[21];
  const float* cew1 = (const float*)d_in[22]; const float* ceb1 = (const float*)d_in[23];
  const float* cew2 = (const float*)d_in[24]; const float* ceb2 = (const float*)d_in[25];
  const float* cew3 = (const float*)d_in[26]; const float* ceb3 = (const float*)d_in[27];
  const float* scm_causal = (const float*)d_in[28];
  const float* mw1 = (const float*)d_in[29]; const float* mb1 = (const float*)d_in[30];
  const float* mw2 = (const float*)d_in[31]; const float* mb2 = (const float*)d_in[32];
  const float* mw3 = (const float*)d_in[33]; const float* mb3 = (const float*)d_in[34];
  const float* nw1 = (const float*)d_in[35]; const float* nb1 = (const float*)d_in[36];
  const float* nw2 = (const float*)d_in[37]; const float* nb2 = (const float*)d_in[38];

  // workspace layout (floats) — total 50,417,664 floats = 192.3 MiB
  float* ws = (float*)d_ws;
  float* Ssm  = ws;               // 16384
  float* cwsm = ws + 16384;       // 4096
  float* wc   = ws + 20480;       // 65536 (reused for all 3 GAT weight repacks)
  float* comm = ws + 86016;       // 4,194,304  (B,N,64)
  float* AI   = ws + 4280320;     // 12,582,912 (B,N,192): ai -> combined -> ce
  float* H1   = ws + 16863232;    // 16,777,216 (B,N,256): xt -> h1 -> partials/h2c
  float* HCG  = ws + 33640448;    // 16,777,216 (B,N,256): xm -> hcg -> h2 -> h1c -> noise

  float* out_actor = (float*)d_out;
  float* out_critic = out_actor + 1048576;
  float* out_cent = out_critic + 65536;
  float* out_scm = out_cent + 65536;

  auto GEMM = [&](const float* A, const float* Bm, const float* bias, float* C,
                  int M, int N, int K, long long lda, long long ldc,
                  long long aBS, long long bBS, long long biasBS, long long cBS,
                  int act, int gz, int kPerSplit) {
    dim3 grid(M / 64, (N + 63) / 64, gz);
    hipLaunchKernelGGL(gemm_k, grid, dim3(256), 0, stream, A, Bm, bias, C, M, N, K,
                       lda, ldc, aBS, bBS, biasBS, cBS, act, kPerSplit);
  };

  // 0) small softmaxes
  hipLaunchKernelGGL(softmax_rows_k, dim3(128), dim3(64), 0, stream, causal, Ssm, 128);
  hipLaunchKernelGGL(softmax_rows_k, dim3(64), dim3(64), 0, stream, scm_causal, cwsm, 64);

  // 1) plain GAT -> comm (init)
  hipLaunchKernelGGL(repack_w_k, dim3((NH * 128 * 64 + 255) / 256), dim3(256), 0, stream, gat_W, wc, 128);
  GEMM(obs, wc, nullptr, H1, 65536, 256, 128, 128, 256, 0, 0, 0, 0, 0, 1, 0);        // xt1
  hipLaunchKernelGGL(gat_attn4_k, dim3(1024), dim3(256), 0, stream, H1, gat_a, adj, comm, 0);

  // 2) causal GAT
  GEMM(obs, Ssm, nullptr, HCG, 65536, 128, 128, 128, 128, 0, 0, 0, 0, 0, 1, 0);      // xm
  hipLaunchKernelGGL(repack_w_k, dim3((NH * 128 * 64 + 255) / 256), dim3(256), 0, stream, cg_W0, wc, 128);
  GEMM(HCG, wc, nullptr, H1, 65536, 256, 128, 128, 256, 0, 0, 0, 0, 0, 1, 0);        // xt_cg0
  hipLaunchKernelGGL(gat_attn4_k, dim3(1024), dim3(256), 0, stream, H1, cg_a0, adj, HCG, 2); // hcg (ELU)
  hipLaunchKernelGGL(repack_w_k, dim3((NH * 256 * 64 + 255) / 256), dim3(256), 0, stream, cg_W1, wc, 256);
  GEMM(HCG, wc, nullptr, H1, 65536, 256, 256, 256, 256, 0, 0, 0, 0, 0, 1, 0);        // xt_cg1
  hipLaunchKernelGGL(gat_attn4_k, dim3(1024), dim3(256), 0, stream, H1, cg_a1, adj, comm, 1);

  // 3) ai = [obs, comm]
  hipLaunchKernelGGL(build_ai_k, dim3((12582912 + 255) / 256), dim3(256), 0, stream, obs, comm, AI);

  // 4) actor MLP (per-agent)
  GEMM(AI, aw1, ab1, H1, 1024, 256, 192, 12288, 16384, 192, 49152, 256, 256, 1, 64, 0);
  GEMM(H1, aw2, ab2, HCG, 1024, 256, 256, 16384, 16384, 256, 65536, 256, 256, 1, 64, 0);
  GEMM(HCG, aw3, ab3, out_actor, 1024, 16, 256, 16384, 1024, 256, 4096, 16, 16, 0, 64, 0);

  // 5) critic MLP (per-agent)
  GEMM(AI, crw1, crb1, H1, 1024, 256, 192, 12288, 16384, 192, 49152, 256, 256, 1, 64, 0);
  GEMM(H1, crw2, crb2, HCG, 1024, 256, 256, 16384, 16384, 256, 65536, 256, 256, 1, 64, 0);
  GEMM(HCG, crw3, crb3, out_critic, 1024, 1, 256, 16384, 64, 256, 256, 1, 1, 0, 64, 0);

  // 6) centralized critic (combined -> AI; ai no longer needed)
  hipLaunchKernelGGL(build_combined_k, dim3((9437184 + 255) / 256), dim3(256), 0, stream, obs, acts, AI);
  GEMM(AI, cew1, nullptr, H1, 1024, 256, 9216, 9216, 256, 0, 0, 0, 262144, 0, 16, 576); // partials
  hipLaunchKernelGGL(reduce_bias_relu_k, dim3(1024), dim3(256), 0, stream, H1, ceb1, HCG);
  GEMM(HCG, cew2, ceb2, H1, 1024, 256, 256, 256, 256, 0, 0, 0, 0, 1, 1, 0);
  GEMM(H1, cew3, ceb3, out_cent, 1024, 64, 256, 256, 64, 0, 0, 0, 0, 0, 1, 0);

  // 7) SCM mechanisms (input = combined in AI)
  GEMM(AI, mw1, mb1, H1, 1024, 256, 144, 9216, 16384, 144, 36864, 256, 256, 1, 64, 0);
  GEMM(H1, mw2, mb2, HCG, 1024, 256, 256, 16384, 16384, 256, 65536, 256, 256, 1, 64, 0);
  GEMM(HCG, mw3, mb3, AI, 1024, 128, 256, 16384, 8192, 256, 32768, 128, 128, 0, 64, 0); // ce -> AI

  // 8) noise model (input = obs)
  GEMM(obs, nw1, nb1, H1, 1024, 256, 128, 8192, 16384, 128, 32768, 256, 256, 1, 64, 0);
  GEMM(H1, nw2, nb2, HCG, 1024, 128, 256, 16384, 8192, 256, 32768, 128, 128, 0, 64, 0); // noise -> HCG

  // 9) scm_pred = softmax(scm_causal) @ ce + noise
  hipLaunchKernelGGL(se_noise_k, dim3(1024), dim3(256), 0, stream, cwsm, AI, HCG, out_scm);
}

// Round 4
// 1193.734 us; speedup vs baseline: 2.2741x; 1.7381x over previous
//
#include <hip/hip_runtime.h>
#include <hip/hip_bf16.h>
#include <math.h>

// Problem constants
#define NB 1024    // batch
#define NAG 64     // agents
#define OBS 128
#define ACTD 16
#define HID 256
#define GD 64
#define NH 4       // heads

typedef short bhalf8 __attribute__((ext_vector_type(8)));
typedef float f32x4 __attribute__((ext_vector_type(4)));

__device__ inline unsigned short f2bf_u(float f) {
  __hip_bfloat16 h = __float2bfloat16(f);
  return *(unsigned short*)&h;
}
__device__ inline unsigned pk2(float x, float y) {
  float2 f2; f2.x = x; f2.y = y;
  __hip_bfloat162 h = __float22bfloat162_rn(f2);
  return *(unsigned*)&h;
}

// ---------------- row softmax ----------------
__global__ __launch_bounds__(64) void softmax_rows_k(const float* __restrict__ in,
                                                     float* __restrict__ out, int n) {
  int row = blockIdx.x;
  int lane = threadIdx.x;
  const float* r = in + (size_t)row * n;
  float m = -INFINITY;
  for (int j = lane; j < n; j += 64) m = fmaxf(m, r[j]);
#pragma unroll
  for (int off = 32; off; off >>= 1) m = fmaxf(m, __shfl_xor(m, off));
  float s = 0.f;
  for (int j = lane; j < n; j += 64) s += expf(r[j] - m);
#pragma unroll
  for (int off = 32; off; off >>= 1) s += __shfl_xor(s, off);
  float inv = 1.f / s;
  for (int j = lane; j < n; j += 64) out[(size_t)row * n + j] = expf(r[j] - m) * inv;
}

// ---------------- batched transpose+cvt: in (Z,K,N) f32 -> out (Z,N,K) bf16 ----------------
__global__ __launch_bounds__(256) void transpose_cvt_k(const float* __restrict__ in,
                                                       unsigned short* __restrict__ out,
                                                       int K, int N) {
  __shared__ float t[32][33];
  int k0 = blockIdx.x * 32, n0 = blockIdx.y * 32, z = blockIdx.z;
  int tx = threadIdx.x, ty = threadIdx.y;  // 32 x 8
  const float* ib = in + (size_t)z * K * N;
  unsigned short* ob = out + (size_t)z * N * K;
#pragma unroll
  for (int i = 0; i < 4; ++i) {
    int k = k0 + ty + 8 * i, n = n0 + tx;
    if (k < K && n < N) t[ty + 8 * i][tx] = ib[(size_t)k * N + n];
  }
  __syncthreads();
#pragma unroll
  for (int i = 0; i < 4; ++i) {
    int n = n0 + ty + 8 * i, k = k0 + tx;
    if (n < N && k < K) ob[(size_t)n * K + k] = f2bf_u(t[tx][ty + 8 * i]);
  }
}

// ---------------- GAT weight repack: W (H,F,D) -> WcT bf16 (H*D, F) ----------------
__global__ void repack_wT_k(const float* __restrict__ W, unsigned short* __restrict__ WcT, int F) {
  int idx = blockIdx.x * 256 + threadIdx.x;
  if (idx >= NH * F * 64) return;
  int d = idx & 63;
  int f = (idx >> 6) % F;
  int h = idx / (F * 64);
  WcT[((size_t)(h * 64 + d)) * F + f] = f2bf_u(W[idx]);
}

// ---------------- bf16 MFMA GEMM ----------------
// C = act(A @ B + bias). A (M,K) f32 row-major stride lda. BT bf16 (N,K) row-major.
// batched via blockIdx.z (aBS/btBS/biasBS/cBS element offsets) or split-K when kPerSplit>0.
__global__ __launch_bounds__(256) void gemm_mfma_k(
    const float* __restrict__ A, const unsigned short* __restrict__ BT,
    const float* __restrict__ bias, float* __restrict__ C,
    int M, int N, int K,
    long long lda, long long ldc,
    long long aBS, long long btBS, long long biasBS, long long cBS,
    int act, int kPerSplit) {
  __shared__ unsigned short As[64 * 40];
  __shared__ unsigned short Bs[64 * 40];
  int tid = threadIdx.x;
  int wave = tid >> 6, lane = tid & 63;
  int m0 = blockIdx.x * 64, n0 = blockIdx.y * 64;
  int z = blockIdx.z;
  const float* Ab;
  const unsigned short* Bb;
  const float* biasb = nullptr;
  float* Cb;
  int k_begin, k_end;
  if (kPerSplit > 0) {
    Ab = A; Bb = BT; Cb = C + (long long)z * cBS;
    k_begin = z * kPerSplit;
    k_end = k_begin + kPerSplit;
    if (k_end > K) k_end = K;
  } else {
    Ab = A + (long long)z * aBS;
    Bb = BT + (long long)z * btBS;
    if (bias) biasb = bias + (long long)z * biasBS;
    Cb = C + (long long)z * cBS;
    k_begin = 0; k_end = K;
  }
  int sr = tid >> 2;         // staging row 0..63 (A: m, B: n)
  int sk = (tid & 3) * 8;    // staging k-seg
  int fr = lane & 15;        // fragment row/col within 16
  int kq = (lane >> 4) * 8;  // fragment k-quad offset

  f32x4 zf = {0.f, 0.f, 0.f, 0.f};
  f32x4 acc[4] = {zf, zf, zf, zf};

  const unsigned short* bRow = Bb + (long long)(n0 + sr) * K;
  bool bValid = (n0 + sr) < N;
  const float* aRow = Ab + (long long)(m0 + sr) * lda;

  for (int k0 = k_begin; k0 < k_end; k0 += 32) {
    int kk = k0 + sk;
    // ---- stage A (f32 -> bf16)
    uint4 aw;
    if (kk + 7 < k_end) {
      const float* ap = aRow + kk;
      float4 v0 = *(const float4*)ap;
      float4 v1 = *(const float4*)(ap + 4);
      aw.x = pk2(v0.x, v0.y); aw.y = pk2(v0.z, v0.w);
      aw.z = pk2(v1.x, v1.y); aw.w = pk2(v1.z, v1.w);
    } else {
      float t[8];
#pragma unroll
      for (int j = 0; j < 8; ++j) t[j] = (kk + j < k_end) ? aRow[kk + j] : 0.f;
      aw.x = pk2(t[0], t[1]); aw.y = pk2(t[2], t[3]);
      aw.z = pk2(t[4], t[5]); aw.w = pk2(t[6], t[7]);
    }
    *(uint4*)&As[sr * 40 + sk] = aw;
    // ---- stage B (bf16 passthrough)
    uint4 bw = {0u, 0u, 0u, 0u};
    if (bValid) {
      if (kk + 7 < k_end) {
        bw = *(const uint4*)(bRow + kk);
      } else {
        unsigned short tb[8];
#pragma unroll
        for (int j = 0; j < 8; ++j) tb[j] = (kk + j < k_end) ? bRow[kk + j] : (unsigned short)0;
        bw.x = (unsigned)tb[0] | ((unsigned)tb[1] << 16);
        bw.y = (unsigned)tb[2] | ((unsigned)tb[3] << 16);
        bw.z = (unsigned)tb[4] | ((unsigned)tb[5] << 16);
        bw.w = (unsigned)tb[6] | ((unsigned)tb[7] << 16);
      }
    }
    *(uint4*)&Bs[sr * 40 + sk] = bw;
    __syncthreads();
    // ---- compute: wave owns rows 16*wave..+15, all 4 n-tiles
    bhalf8 af = *(bhalf8*)&As[(16 * wave + fr) * 40 + kq];
#pragma unroll
    for (int t = 0; t < 4; ++t) {
      bhalf8 bf = *(bhalf8*)&Bs[(16 * t + fr) * 40 + kq];
      acc[t] = __builtin_amdgcn_mfma_f32_16x16x32_bf16(af, bf, acc[t], 0, 0, 0);
    }
    __syncthreads();
  }
  // ---- epilogue
  int rb = (lane >> 4) * 4;
#pragma unroll
  for (int t = 0; t < 4; ++t) {
    int col = n0 + 16 * t + fr;
    if (col < N) {
      float bv = biasb ? biasb[col] : 0.f;
#pragma unroll
      for (int r = 0; r < 4; ++r) {
        long long row = m0 + 16 * wave + rb + r;
        float v = acc[t][r] + bv;
        if (act == 1) v = fmaxf(v, 0.f);
        Cb[row * ldc + col] = v;
      }
    }
  }
}

// ---------------- GAT attention, 4 waves per graph, head loop inside ----------------
// xt layout: (B*N, NH*GD). mode: 0 = comm = 0.25*sum_h att ; 1 = comm += ; 2 = concat+ELU
__global__ __launch_bounds__(256) void gat_attn4_k(
    const float* __restrict__ xt, const float* __restrict__ a,
    const float* __restrict__ adj, float* __restrict__ out, int mode) {
  int b = blockIdx.x;
  int tid = threadIdx.x;
  int wave = tid >> 6, lane = tid & 63;
  __shared__ float xs[64][68];
  __shared__ float wsT[64][68];
  __shared__ float si[64], sj[64];

  const float* adjb = adj + (size_t)b * 4096;
  float adjv[16];
#pragma unroll
  for (int r = 0; r < 16; ++r) adjv[r] = adjb[(size_t)(wave * 16 + r) * 64 + lane];

  float accm[16];
  int lrow = tid >> 2;
  int cg = tid & 3;

  for (int h = 0; h < 4; ++h) {
    const float* xrow = xt + ((size_t)(b * 64 + lrow)) * 256 + h * 64 + cg * 16;
    const float* ah = a + h * 128;
    float p1 = 0.f, p2 = 0.f;
#pragma unroll
    for (int q = 0; q < 4; ++q) {
      float4 v = *(const float4*)(xrow + 4 * q);
      int c = cg * 16 + 4 * q;
      xs[lrow][c + 0] = v.x; xs[lrow][c + 1] = v.y;
      xs[lrow][c + 2] = v.z; xs[lrow][c + 3] = v.w;
      p1 += v.x * ah[c] + v.y * ah[c + 1] + v.z * ah[c + 2] + v.w * ah[c + 3];
      p2 += v.x * ah[64 + c] + v.y * ah[64 + c + 1] + v.z * ah[64 + c + 2] + v.w * ah[64 + c + 3];
    }
    p1 += __shfl_xor(p1, 1); p1 += __shfl_xor(p1, 2);
    p2 += __shfl_xor(p2, 1); p2 += __shfl_xor(p2, 2);
    if (cg == 0) { si[lrow] = p1; sj[lrow] = p2; }
    __syncthreads();

#pragma unroll
    for (int r = 0; r < 16; ++r) {
      int i = wave * 16 + r;
      float e = si[i] + sj[lane];
      e = e > 0.f ? e : 0.2f * e;
      if (adjv[r] == 0.f) e = -INFINITY;
      float mx = e;
#pragma unroll
      for (int off = 32; off; off >>= 1) mx = fmaxf(mx, __shfl_xor(mx, off));
      float p = (e == -INFINITY) ? 0.f : expf(e - mx);
      float sm = p;
#pragma unroll
      for (int off = 32; off; off >>= 1) sm += __shfl_xor(sm, off);
      wsT[lane][i] = (sm > 0.f) ? p / sm : 0.f;
    }

    float acc[16];
#pragma unroll
    for (int r = 0; r < 16; ++r) acc[r] = 0.f;
    for (int j = 0; j < 64; ++j) {
      float xv = xs[j][lane];
#pragma unroll
      for (int r4 = 0; r4 < 4; ++r4) {
        float4 w4 = *(const float4*)&wsT[j][wave * 16 + r4 * 4];
        acc[r4 * 4 + 0] += w4.x * xv;
        acc[r4 * 4 + 1] += w4.y * xv;
        acc[r4 * 4 + 2] += w4.z * xv;
        acc[r4 * 4 + 3] += w4.w * xv;
      }
    }
    if (mode == 2) {
#pragma unroll
      for (int r = 0; r < 16; ++r) {
        int i = wave * 16 + r;
        float v = acc[r];
        v = v > 0.f ? v : expf(v) - 1.f;
        out[((size_t)(b * 64 + i)) * 256 + h * 64 + lane] = v;
      }
    } else {
#pragma unroll
      for (int r = 0; r < 16; ++r) {
        if (h == 0) accm[r] = 0.25f * acc[r];
        else accm[r] += 0.25f * acc[r];
      }
    }
    __syncthreads();
  }

  if (mode != 2) {
    float* cb = out + (size_t)b * 4096;
#pragma unroll
    for (int r = 0; r < 16; ++r) {
      int i = wave * 16 + r;
      if (mode == 1) cb[i * 64 + lane] += accm[r];
      else cb[i * 64 + lane] = accm[r];
    }
  }
}

// ---------------- ai = [obs, comm] (B,N,192) ----------------
__global__ void build_ai_k(const float* __restrict__ obs, const float* __restrict__ comm,
                           float* __restrict__ ai) {
  size_t idx = (size_t)blockIdx.x * 256 + threadIdx.x;
  if (idx >= (size_t)NB * NAG * 192) return;
  int c = (int)(idx % 192);
  size_t bn = idx / 192;
  ai[idx] = (c < 128) ? obs[bn * 128 + c] : comm[bn * 64 + (c - 128)];
}

// ---------------- combined = [obs, actions] (B,N,144) ----------------
__global__ void build_combined_k(const float* __restrict__ obs, const float* __restrict__ act,
                                 float* __restrict__ cmb) {
  size_t idx = (size_t)blockIdx.x * 256 + threadIdx.x;
  if (idx >= (size_t)NB * NAG * 144) return;
  int c = (int)(idx % 144);
  size_t bn = idx / 144;
  cmb[idx] = (c < 128) ? obs[bn * 128 + c] : act[bn * 16 + (c - 128)];
}

// ---------------- split-K reduce + bias + relu for cent l1 ----------------
__global__ void reduce_bias_relu_k(const float* __restrict__ part, const float* __restrict__ bias,
                                   float* __restrict__ out) {
  int idx = blockIdx.x * 256 + threadIdx.x;
  float s = 0.f;
#pragma unroll
  for (int zz = 0; zz < 16; ++zz) s += part[(size_t)zz * 262144 + idx];
  s += bias[idx & 255];
  out[idx] = fmaxf(s, 0.f);
}

// ---------------- scm_pred = cw @ ce + noise ----------------
__global__ __launch_bounds__(256) void se_noise_k(const float* __restrict__ cw,
                                                  const float* __restrict__ ce,
                                                  const float* __restrict__ nz,
                                                  float* __restrict__ out) {
  int b = blockIdx.x;
  __shared__ float ceL[64 * 128];
  __shared__ float cwL[64 * 64];
  const float* cb = ce + (size_t)b * 8192;
  for (int idx = threadIdx.x; idx < 8192; idx += 256) ceL[idx] = cb[idx];
  for (int idx = threadIdx.x; idx < 4096; idx += 256) cwL[idx] = cw[idx];
  __syncthreads();
  for (int idx = threadIdx.x; idx < 8192; idx += 256) {
    int i = idx >> 7, d = idx & 127;
    float acc = 0.f;
    for (int j = 0; j < 64; ++j) acc += cwL[i * 64 + j] * ceL[j * 128 + d];
    out[(size_t)b * 8192 + idx] = acc + nz[(size_t)b * 8192 + idx];
  }
}

extern "C" void kernel_launch(void* const* d_in, const int* in_sizes, int n_in,
                              void* d_out, int out_size, void* d_ws, size_t ws_size,
                              hipStream_t stream) {
  (void)in_sizes; (void)n_in; (void)out_size; (void)ws_size;
  const float* obs = (const float*)d_in[0];
  const float* acts = (const float*)d_in[1];
  const float* adj = (const float*)d_in[2];
  const float* causal = (const float*)d_in[3];
  const float* gat_W = (const float*)d_in[4];
  const float* gat_a = (const float*)d_in[5];
  const float* cg_W0 = (const float*)d_in[6];
  const float* cg_a0 = (const float*)d_in[7];
  const float* cg_W1 = (const float*)d_in[8];
  const float* cg_a1 = (const float*)d_in[9];
  const float* aw1 = (const float*)d_in[10]; const float* ab1 = (const float*)d_in[11];
  const float* aw2 = (const float*)d_in[12]; const float* ab2 = (const float*)d_in[13];
  const float* aw3 = (const float*)d_in[14]; const float* ab3 = (const float*)d_in[15];
  const float* crw1 = (const float*)d_in[16]; const float* crb1 = (const float*)d_in[17];
  const float* crw2 = (const float*)d_in[18]; const float* crb2 = (const float*)d_in[19];
  const float* crw3 = (const float*)d_in[20]; const float* crb3 = (const float*)d_in[21];
  const float* cew1 = (const float*)d_in[22]; const float* ceb1 = (const float*)d_in[23];
  const float* cew2 = (const float*)d_in[24]; const float* ceb2 = (const float*)d_in[25];
  const float* cew3 = (const float*)d_in[26]; const float* ceb3 = (const float*)d_in[27];
  const float* scm_causal = (const float*)d_in[28];
  const float* mw1 = (const float*)d_in[29]; const float* mb1 = (const float*)d_in[30];
  const float* mw2 = (const float*)d_in[31]; const float* mb2 = (const float*)d_in[32];
  const float* mw3 = (const float*)d_in[33]; const float* mb3 = (const float*)d_in[34];
  const float* nw1 = (const float*)d_in[35]; const float* nb1 = (const float*)d_in[36];
  const float* nw2 = (const float*)d_in[37]; const float* nb2 = (const float*)d_in[38];

  // workspace layout (floats); total 65,515,520 floats = 249.9 MiB
  float* ws = (float*)d_ws;
  float* Ssm  = ws;               // 16384
  float* cwsm = ws + 16384;       // 4096
  float* comm = ws + 20480;       // 4,194,304  (B,N,64)
  float* AI   = ws + 4214784;     // 12,582,912 (B,N,192): ai -> combined -> ce
  float* H1   = ws + 16797696;    // 16,777,216 (B,N,256)
  float* HCG  = ws + 33574912;    // 16,777,216 (B,N,256)
  unsigned short* wbf = (unsigned short*)(ws + 50352128);  // bf16 weights, 30,326,784 ushorts
  unsigned short* SsmT  = wbf;             // 16384
  unsigned short* wcT   = wbf + 16384;     // 65536 (reused per GAT layer)
  unsigned short* aw1T  = wbf + 81920;     // 3,145,728
  unsigned short* aw2T  = wbf + 3227648;   // 4,194,304
  unsigned short* aw3T  = wbf + 7421952;   // 262,144
  unsigned short* crw1T = wbf + 7684096;   // 3,145,728
  unsigned short* crw2T = wbf + 10829824;  // 4,194,304
  unsigned short* crw3T = wbf + 15024128;  // 16,384
  unsigned short* cew1T = wbf + 15040512;  // 2,359,296
  unsigned short* cew2T = wbf + 17399808;  // 65,536
  unsigned short* cew3T = wbf + 17465344;  // 16,384
  unsigned short* mw1T  = wbf + 17481728;  // 2,359,296
  unsigned short* mw2T  = wbf + 19841024;  // 4,194,304
  unsigned short* mw3T  = wbf + 24035328;  // 2,097,152
  unsigned short* nw1T  = wbf + 26132480;  // 2,097,152
  unsigned short* nw2T  = wbf + 28229632;  // 2,097,152

  float* out_actor = (float*)d_out;
  float* out_critic = out_actor + 1048576;
  float* out_cent = out_critic + 65536;
  float* out_scm = out_cent + 65536;

  auto GEMM = [&](const float* A, const unsigned short* BT, const float* bias, float* C,
                  int M, int N, int K, long long lda, long long ldc,
                  long long aBS, long long btBS, long long biasBS, long long cBS,
                  int act, int gz, int kPerSplit) {
    dim3 grid(M / 64, (N + 63) / 64, gz);
    hipLaunchKernelGGL(gemm_mfma_k, grid, dim3(256), 0, stream, A, BT, bias, C, M, N, K,
                       lda, ldc, aBS, btBS, biasBS, cBS, act, kPerSplit);
  };
  auto TRN = [&](const float* in, unsigned short* out, int Z, int K, int N) {
    dim3 grid((K + 31) / 32, (N + 31) / 32, Z);
    hipLaunchKernelGGL(transpose_cvt_k, grid, dim3(32, 8), 0, stream, in, out, K, N);
  };

  // 0) small softmaxes + weight conversions (one-time per launch)
  hipLaunchKernelGGL(softmax_rows_k, dim3(128), dim3(64), 0, stream, causal, Ssm, 128);
  hipLaunchKernelGGL(softmax_rows_k, dim3(64), dim3(64), 0, stream, scm_causal, cwsm, 64);
  TRN(Ssm, SsmT, 1, 128, 128);
  TRN(aw1, aw1T, 64, 192, 256);  TRN(aw2, aw2T, 64, 256, 256);  TRN(aw3, aw3T, 64, 256, 16);
  TRN(crw1, crw1T, 64, 192, 256); TRN(crw2, crw2T, 64, 256, 256); TRN(crw3, crw3T, 64, 256, 1);
  TRN(cew1, cew1T, 1, 9216, 256); TRN(cew2, cew2T, 1, 256, 256);  TRN(cew3, cew3T, 1, 256, 64);
  TRN(mw1, mw1T, 64, 144, 256);  TRN(mw2, mw2T, 64, 256, 256);  TRN(mw3, mw3T, 64, 256, 128);
  TRN(nw1, nw1T, 64, 128, 256);  TRN(nw2, nw2T, 64, 256, 128);

  // 1) plain GAT -> comm (init)
  hipLaunchKernelGGL(repack_wT_k, dim3((NH * 128 * 64 + 255) / 256), dim3(256), 0, stream, gat_W, wcT, 128);
  GEMM(obs, wcT, nullptr, H1, 65536, 256, 128, 128, 256, 0, 0, 0, 0, 0, 1, 0);        // xt1
  hipLaunchKernelGGL(gat_attn4_k, dim3(1024), dim3(256), 0, stream, H1, gat_a, adj, comm, 0);

  // 2) causal GAT
  GEMM(obs, SsmT, nullptr, HCG, 65536, 128, 128, 128, 128, 0, 0, 0, 0, 0, 1, 0);      // xm
  hipLaunchKernelGGL(repack_wT_k, dim3((NH * 128 * 64 + 255) / 256), dim3(256), 0, stream, cg_W0, wcT, 128);
  GEMM(HCG, wcT, nullptr, H1, 65536, 256, 128, 128, 256, 0, 0, 0, 0, 0, 1, 0);        // xt_cg0
  hipLaunchKernelGGL(gat_attn4_k, dim3(1024), dim3(256), 0, stream, H1, cg_a0, adj, HCG, 2); // hcg (ELU)
  hipLaunchKernelGGL(repack_wT_k, dim3((NH * 256 * 64 + 255) / 256), dim3(256), 0, stream, cg_W1, wcT, 256);
  GEMM(HCG, wcT, nullptr, H1, 65536, 256, 256, 256, 256, 0, 0, 0, 0, 0, 1, 0);        // xt_cg1
  hipLaunchKernelGGL(gat_attn4_k, dim3(1024), dim3(256), 0, stream, H1, cg_a1, adj, comm, 1);

  // 3) ai = [obs, comm]
  hipLaunchKernelGGL(build_ai_k, dim3((12582912 + 255) / 256), dim3(256), 0, stream, obs, comm, AI);

  // 4) actor MLP (per-agent)
  GEMM(AI, aw1T, ab1, H1, 1024, 256, 192, 12288, 16384, 192, 49152, 256, 256, 1, 64, 0);
  GEMM(H1, aw2T, ab2, HCG, 1024, 256, 256, 16384, 16384, 256, 65536, 256, 256, 1, 64, 0);
  GEMM(HCG, aw3T, ab3, out_actor, 1024, 16, 256, 16384, 1024, 256, 4096, 16, 16, 0, 64, 0);

  // 5) critic MLP (per-agent)
  GEMM(AI, crw1T, crb1, H1, 1024, 256, 192, 12288, 16384, 192, 49152, 256, 256, 1, 64, 0);
  GEMM(H1, crw2T, crb2, HCG, 1024, 256, 256, 16384, 16384, 256, 65536, 256, 256, 1, 64, 0);
  GEMM(HCG, crw3T, crb3, out_critic, 1024, 1, 256, 16384, 64, 256, 256, 1, 1, 0, 64, 0);

  // 6) centralized critic (combined -> AI)
  hipLaunchKernelGGL(build_combined_k, dim3((9437184 + 255) / 256), dim3(256), 0, stream, obs, acts, AI);
  GEMM(AI, cew1T, nullptr, H1, 1024, 256, 9216, 9216, 256, 0, 0, 0, 262144, 0, 16, 576);
  hipLaunchKernelGGL(reduce_bias_relu_k, dim3(1024), dim3(256), 0, stream, H1, ceb1, HCG);
  GEMM(HCG, cew2T, ceb2, H1, 1024, 256, 256, 256, 256, 0, 0, 0, 0, 1, 1, 0);
  GEMM(H1, cew3T, ceb3, out_cent, 1024, 64, 256, 256, 64, 0, 0, 0, 0, 0, 1, 0);

  // 7) SCM mechanisms (input = combined in AI)
  GEMM(AI, mw1T, mb1, H1, 1024, 256, 144, 9216, 16384, 144, 36864, 256, 256, 1, 64, 0);
  GEMM(H1, mw2T, mb2, HCG, 1024, 256, 256, 16384, 16384, 256, 65536, 256, 256, 1, 64, 0);
  GEMM(HCG, mw3T, mb3, AI, 1024, 128, 256, 16384, 8192, 256, 32768, 128, 128, 0, 64, 0); // ce -> AI

  // 8) noise model (input = obs)
  GEMM(obs, nw1T, nb1, H1, 1024, 256, 128, 8192, 16384, 128, 32768, 256, 256, 1, 64, 0);
  GEMM(H1, nw2T, nb2, HCG, 1024, 128, 256, 16384, 8192, 256, 32768, 128, 128, 0, 64, 0); // noise -> HCG

  // 9) scm_pred = softmax(scm_causal) @ ce + noise
  hipLaunchKernelGGL(se_noise_k, dim3(1024), dim3(256), 0, stream, cwsm, AI, HCG, out_scm);
}

// Round 5
// 1186.226 us; speedup vs baseline: 2.2885x; 1.0063x over previous
//
#include <hip/hip_runtime.h>
#include <hip/hip_bf16.h>
#include <math.h>

// Problem constants
#define NB 1024    // batch
#define NAG 64     // agents
#define OBS 128
#define ACTD 16
#define HID 256
#define GD 64
#define NH 4       // heads

typedef short bhalf8 __attribute__((ext_vector_type(8)));
typedef float f32x4 __attribute__((ext_vector_type(4)));

__device__ inline unsigned short f2bf_u(float f) {
  __hip_bfloat16 h = __float2bfloat16(f);
  return *(unsigned short*)&h;
}
__device__ inline unsigned pk2(float x, float y) {
  float2 f2; f2.x = x; f2.y = y;
  __hip_bfloat162 h = __float22bfloat162_rn(f2);
  return *(unsigned*)&h;
}

// ---------------- row softmax ----------------
__global__ __launch_bounds__(64) void softmax_rows_k(const float* __restrict__ in,
                                                     float* __restrict__ out, int n) {
  int row = blockIdx.x;
  int lane = threadIdx.x;
  const float* r = in + (size_t)row * n;
  float m = -INFINITY;
  for (int j = lane; j < n; j += 64) m = fmaxf(m, r[j]);
#pragma unroll
  for (int off = 32; off; off >>= 1) m = fmaxf(m, __shfl_xor(m, off));
  float s = 0.f;
  for (int j = lane; j < n; j += 64) s += expf(r[j] - m);
#pragma unroll
  for (int off = 32; off; off >>= 1) s += __shfl_xor(s, off);
  float inv = 1.f / s;
  for (int j = lane; j < n; j += 64) out[(size_t)row * n + j] = expf(r[j] - m) * inv;
}

// ---------------- batched transpose+cvt: in (Z,K,N) f32 -> out (Z,N,K) bf16 ----------------
__global__ __launch_bounds__(256) void transpose_cvt_k(const float* __restrict__ in,
                                                       unsigned short* __restrict__ out,
                                                       int K, int N) {
  __shared__ float t[32][33];
  int k0 = blockIdx.x * 32, n0 = blockIdx.y * 32, z = blockIdx.z;
  int tx = threadIdx.x, ty = threadIdx.y;  // 32 x 8
  const float* ib = in + (size_t)z * K * N;
  unsigned short* ob = out + (size_t)z * N * K;
#pragma unroll
  for (int i = 0; i < 4; ++i) {
    int k = k0 + ty + 8 * i, n = n0 + tx;
    if (k < K && n < N) t[ty + 8 * i][tx] = ib[(size_t)k * N + n];
  }
  __syncthreads();
#pragma unroll
  for (int i = 0; i < 4; ++i) {
    int n = n0 + ty + 8 * i, k = k0 + tx;
    if (n < N && k < K) ob[(size_t)n * K + k] = f2bf_u(t[tx][ty + 8 * i]);
  }
}

// ---------------- GAT weight repack: W (H,F,D) -> WcT bf16 (H*D, F) ----------------
__global__ void repack_wT_k(const float* __restrict__ W, unsigned short* __restrict__ WcT, int F) {
  int idx = blockIdx.x * 256 + threadIdx.x;
  if (idx >= NH * F * 64) return;
  int d = idx & 63;
  int f = (idx >> 6) % F;
  int h = idx / (F * 64);
  WcT[((size_t)(h * 64 + d)) * F + f] = f2bf_u(W[idx]);
}

// ---------------- bf16 MFMA GEMM, 64x64 tile (small-N cases) ----------------
__global__ __launch_bounds__(256) void gemm_mfma_k(
    const float* __restrict__ A, const unsigned short* __restrict__ BT,
    const float* __restrict__ bias, float* __restrict__ C,
    int M, int N, int K,
    long long lda, long long ldc,
    long long aBS, long long btBS, long long biasBS, long long cBS,
    int act, int kPerSplit) {
  __shared__ unsigned short As[64 * 40];
  __shared__ unsigned short Bs[64 * 40];
  int tid = threadIdx.x;
  int wave = tid >> 6, lane = tid & 63;
  int m0 = blockIdx.x * 64, n0 = blockIdx.y * 64;
  int z = blockIdx.z;
  const float* Ab;
  const unsigned short* Bb;
  const float* biasb = nullptr;
  float* Cb;
  int k_begin, k_end;
  if (kPerSplit > 0) {
    Ab = A; Bb = BT; Cb = C + (long long)z * cBS;
    k_begin = z * kPerSplit;
    k_end = k_begin + kPerSplit;
    if (k_end > K) k_end = K;
  } else {
    Ab = A + (long long)z * aBS;
    Bb = BT + (long long)z * btBS;
    if (bias) biasb = bias + (long long)z * biasBS;
    Cb = C + (long long)z * cBS;
    k_begin = 0; k_end = K;
  }
  int sr = tid >> 2;
  int sk = (tid & 3) * 8;
  int fr = lane & 15;
  int kq = (lane >> 4) * 8;

  f32x4 zf = {0.f, 0.f, 0.f, 0.f};
  f32x4 acc[4] = {zf, zf, zf, zf};

  const unsigned short* bRow = Bb + (long long)(n0 + sr) * K;
  bool bValid = (n0 + sr) < N;
  const float* aRow = Ab + (long long)(m0 + sr) * lda;

  for (int k0 = k_begin; k0 < k_end; k0 += 32) {
    int kk = k0 + sk;
    uint4 aw;
    if (kk + 7 < k_end) {
      const float* ap = aRow + kk;
      float4 v0 = *(const float4*)ap;
      float4 v1 = *(const float4*)(ap + 4);
      aw.x = pk2(v0.x, v0.y); aw.y = pk2(v0.z, v0.w);
      aw.z = pk2(v1.x, v1.y); aw.w = pk2(v1.z, v1.w);
    } else {
      float t[8];
#pragma unroll
      for (int j = 0; j < 8; ++j) t[j] = (kk + j < k_end) ? aRow[kk + j] : 0.f;
      aw.x = pk2(t[0], t[1]); aw.y = pk2(t[2], t[3]);
      aw.z = pk2(t[4], t[5]); aw.w = pk2(t[6], t[7]);
    }
    *(uint4*)&As[sr * 40 + sk] = aw;
    uint4 bw = {0u, 0u, 0u, 0u};
    if (bValid) {
      if (kk + 7 < k_end) {
        bw = *(const uint4*)(bRow + kk);
      } else {
        unsigned short tb[8];
#pragma unroll
        for (int j = 0; j < 8; ++j) tb[j] = (kk + j < k_end) ? bRow[kk + j] : (unsigned short)0;
        bw.x = (unsigned)tb[0] | ((unsigned)tb[1] << 16);
        bw.y = (unsigned)tb[2] | ((unsigned)tb[3] << 16);
        bw.z = (unsigned)tb[4] | ((unsigned)tb[5] << 16);
        bw.w = (unsigned)tb[6] | ((unsigned)tb[7] << 16);
      }
    }
    *(uint4*)&Bs[sr * 40 + sk] = bw;
    __syncthreads();
    bhalf8 af = *(bhalf8*)&As[(16 * wave + fr) * 40 + kq];
#pragma unroll
    for (int t = 0; t < 4; ++t) {
      bhalf8 bf = *(bhalf8*)&Bs[(16 * t + fr) * 40 + kq];
      acc[t] = __builtin_amdgcn_mfma_f32_16x16x32_bf16(af, bf, acc[t], 0, 0, 0);
    }
    __syncthreads();
  }
  int rb = (lane >> 4) * 4;
#pragma unroll
  for (int t = 0; t < 4; ++t) {
    int col = n0 + 16 * t + fr;
    if (col < N) {
      float bv = biasb ? biasb[col] : 0.f;
#pragma unroll
      for (int r = 0; r < 4; ++r) {
        long long row = m0 + 16 * wave + rb + r;
        float v = acc[t][r] + bv;
        if (act == 1) v = fmaxf(v, 0.f);
        Cb[row * ldc + col] = v;
      }
    }
  }
}

// ---------------- bf16 MFMA GEMM, 128x128 tile, 4x4 16x16 tiles per wave ----------------
// Requires M % 128 == 0. N guarded. A (M,K) f32; BT (N,K) bf16.
__global__ __launch_bounds__(256) void gemm_mfma128_k(
    const float* __restrict__ A, const unsigned short* __restrict__ BT,
    const float* __restrict__ bias, float* __restrict__ C,
    int M, int N, int K,
    long long lda, long long ldc,
    long long aBS, long long btBS, long long biasBS, long long cBS,
    int act, int kPerSplit) {
  __shared__ unsigned short As[128 * 40];
  __shared__ unsigned short Bs[128 * 40];
  int tid = threadIdx.x;
  int wave = tid >> 6, lane = tid & 63;
  int m0 = blockIdx.x * 128, n0 = blockIdx.y * 128;
  int z = blockIdx.z;
  const float* Ab;
  const unsigned short* Bb;
  const float* biasb = nullptr;
  float* Cb;
  int k_begin, k_end;
  if (kPerSplit > 0) {
    Ab = A; Bb = BT; Cb = C + (long long)z * cBS;
    k_begin = z * kPerSplit;
    k_end = k_begin + kPerSplit;
    if (k_end > K) k_end = K;
  } else {
    Ab = A + (long long)z * aBS;
    Bb = BT + (long long)z * btBS;
    if (bias) biasb = bias + (long long)z * biasBS;
    Cb = C + (long long)z * cBS;
    k_begin = 0; k_end = K;
  }
  int sr = tid >> 1;          // staging row 0..127
  int sk = (tid & 1) * 16;    // k-half
  int mq = (wave >> 1) * 64;  // wave quadrant
  int nq = (wave & 1) * 64;
  int fr = lane & 15;
  int kq = (lane >> 4) * 8;

  f32x4 zf = {0.f, 0.f, 0.f, 0.f};
  f32x4 acc[4][4];
#pragma unroll
  for (int i = 0; i < 4; ++i)
#pragma unroll
    for (int j = 0; j < 4; ++j) acc[i][j] = zf;

  const float* aRow = Ab + (long long)(m0 + sr) * lda;
  const unsigned short* bRow = Bb + (long long)(n0 + sr) * K;
  bool bValid = (n0 + sr) < N;

  for (int k0 = k_begin; k0 < k_end; k0 += 32) {
    int kk = k0 + sk;
    // ---- stage A: 16 floats -> bf16
    uint4 aw0, aw1;
    if (kk + 15 < k_end) {
      const float* ap = aRow + kk;
      float4 v0 = *(const float4*)ap;
      float4 v1 = *(const float4*)(ap + 4);
      float4 v2 = *(const float4*)(ap + 8);
      float4 v3 = *(const float4*)(ap + 12);
      aw0.x = pk2(v0.x, v0.y); aw0.y = pk2(v0.z, v0.w);
      aw0.z = pk2(v1.x, v1.y); aw0.w = pk2(v1.z, v1.w);
      aw1.x = pk2(v2.x, v2.y); aw1.y = pk2(v2.z, v2.w);
      aw1.z = pk2(v3.x, v3.y); aw1.w = pk2(v3.z, v3.w);
    } else {
      float t[16];
#pragma unroll
      for (int j = 0; j < 16; ++j) t[j] = (kk + j < k_end) ? aRow[kk + j] : 0.f;
      aw0.x = pk2(t[0], t[1]);   aw0.y = pk2(t[2], t[3]);
      aw0.z = pk2(t[4], t[5]);   aw0.w = pk2(t[6], t[7]);
      aw1.x = pk2(t[8], t[9]);   aw1.y = pk2(t[10], t[11]);
      aw1.z = pk2(t[12], t[13]); aw1.w = pk2(t[14], t[15]);
    }
    *(uint4*)&As[sr * 40 + sk] = aw0;
    *(uint4*)&As[sr * 40 + sk + 8] = aw1;
    // ---- stage B: 16 bf16 passthrough
    uint4 bw0 = {0u, 0u, 0u, 0u}, bw1 = {0u, 0u, 0u, 0u};
    if (bValid) {
      if (kk + 15 < k_end) {
        bw0 = *(const uint4*)(bRow + kk);
        bw1 = *(const uint4*)(bRow + kk + 8);
      } else {
        unsigned short tb[16];
#pragma unroll
        for (int j = 0; j < 16; ++j) tb[j] = (kk + j < k_end) ? bRow[kk + j] : (unsigned short)0;
        bw0.x = (unsigned)tb[0] | ((unsigned)tb[1] << 16);
        bw0.y = (unsigned)tb[2] | ((unsigned)tb[3] << 16);
        bw0.z = (unsigned)tb[4] | ((unsigned)tb[5] << 16);
        bw0.w = (unsigned)tb[6] | ((unsigned)tb[7] << 16);
        bw1.x = (unsigned)tb[8] | ((unsigned)tb[9] << 16);
        bw1.y = (unsigned)tb[10] | ((unsigned)tb[11] << 16);
        bw1.z = (unsigned)tb[12] | ((unsigned)tb[13] << 16);
        bw1.w = (unsigned)tb[14] | ((unsigned)tb[15] << 16);
      }
    }
    *(uint4*)&Bs[sr * 40 + sk] = bw0;
    *(uint4*)&Bs[sr * 40 + sk + 8] = bw1;
    __syncthreads();
    // ---- compute: 4x4 tiles, 16 MFMA per iter per wave
    bhalf8 af[4], bf[4];
#pragma unroll
    for (int i = 0; i < 4; ++i) af[i] = *(bhalf8*)&As[(mq + 16 * i + fr) * 40 + kq];
#pragma unroll
    for (int j = 0; j < 4; ++j) bf[j] = *(bhalf8*)&Bs[(nq + 16 * j + fr) * 40 + kq];
#pragma unroll
    for (int i = 0; i < 4; ++i)
#pragma unroll
      for (int j = 0; j < 4; ++j)
        acc[i][j] = __builtin_amdgcn_mfma_f32_16x16x32_bf16(af[i], bf[j], acc[i][j], 0, 0, 0);
    __syncthreads();
  }
  // ---- epilogue
  int rb = (lane >> 4) * 4;
#pragma unroll
  for (int j = 0; j < 4; ++j) {
    int col = n0 + nq + 16 * j + fr;
    if (col < N) {
      float bv = biasb ? biasb[col] : 0.f;
#pragma unroll
      for (int i = 0; i < 4; ++i) {
#pragma unroll
        for (int r = 0; r < 4; ++r) {
          long long row = m0 + mq + 16 * i + rb + r;
          float v = acc[i][j][r] + bv;
          if (act == 1) v = fmaxf(v, 0.f);
          Cb[row * ldc + col] = v;
        }
      }
    }
  }
}

// ---------------- GAT attention, 4 waves per graph, head loop inside ----------------
// xt layout: (B*N, NH*GD). mode: 0 = comm = 0.25*sum_h att ; 1 = comm += ; 2 = concat+ELU
__global__ __launch_bounds__(256) void gat_attn4_k(
    const float* __restrict__ xt, const float* __restrict__ a,
    const float* __restrict__ adj, float* __restrict__ out, int mode) {
  int b = blockIdx.x;
  int tid = threadIdx.x;
  int wave = tid >> 6, lane = tid & 63;
  __shared__ float xs[64][68];
  __shared__ float wsT[64][68];
  __shared__ float si[64], sj[64];

  const float* adjb = adj + (size_t)b * 4096;
  float adjv[16];
#pragma unroll
  for (int r = 0; r < 16; ++r) adjv[r] = adjb[(size_t)(wave * 16 + r) * 64 + lane];

  float accm[16];
  int lrow = tid >> 2;
  int cg = tid & 3;

  for (int h = 0; h < 4; ++h) {
    const float* xrow = xt + ((size_t)(b * 64 + lrow)) * 256 + h * 64 + cg * 16;
    const float* ah = a + h * 128;
    float p1 = 0.f, p2 = 0.f;
#pragma unroll
    for (int q = 0; q < 4; ++q) {
      float4 v = *(const float4*)(xrow + 4 * q);
      int c = cg * 16 + 4 * q;
      xs[lrow][c + 0] = v.x; xs[lrow][c + 1] = v.y;
      xs[lrow][c + 2] = v.z; xs[lrow][c + 3] = v.w;
      p1 += v.x * ah[c] + v.y * ah[c + 1] + v.z * ah[c + 2] + v.w * ah[c + 3];
      p2 += v.x * ah[64 + c] + v.y * ah[64 + c + 1] + v.z * ah[64 + c + 2] + v.w * ah[64 + c + 3];
    }
    p1 += __shfl_xor(p1, 1); p1 += __shfl_xor(p1, 2);
    p2 += __shfl_xor(p2, 1); p2 += __shfl_xor(p2, 2);
    if (cg == 0) { si[lrow] = p1; sj[lrow] = p2; }
    __syncthreads();

#pragma unroll
    for (int r = 0; r < 16; ++r) {
      int i = wave * 16 + r;
      float e = si[i] + sj[lane];
      e = e > 0.f ? e : 0.2f * e;
      if (adjv[r] == 0.f) e = -INFINITY;
      float mx = e;
#pragma unroll
      for (int off = 32; off; off >>= 1) mx = fmaxf(mx, __shfl_xor(mx, off));
      float p = (e == -INFINITY) ? 0.f : expf(e - mx);
      float sm = p;
#pragma unroll
      for (int off = 32; off; off >>= 1) sm += __shfl_xor(sm, off);
      wsT[lane][i] = (sm > 0.f) ? p / sm : 0.f;
    }

    float acc[16];
#pragma unroll
    for (int r = 0; r < 16; ++r) acc[r] = 0.f;
    for (int j = 0; j < 64; ++j) {
      float xv = xs[j][lane];
#pragma unroll
      for (int r4 = 0; r4 < 4; ++r4) {
        float4 w4 = *(const float4*)&wsT[j][wave * 16 + r4 * 4];
        acc[r4 * 4 + 0] += w4.x * xv;
        acc[r4 * 4 + 1] += w4.y * xv;
        acc[r4 * 4 + 2] += w4.z * xv;
        acc[r4 * 4 + 3] += w4.w * xv;
      }
    }
    if (mode == 2) {
#pragma unroll
      for (int r = 0; r < 16; ++r) {
        int i = wave * 16 + r;
        float v = acc[r];
        v = v > 0.f ? v : expf(v) - 1.f;
        out[((size_t)(b * 64 + i)) * 256 + h * 64 + lane] = v;
      }
    } else {
#pragma unroll
      for (int r = 0; r < 16; ++r) {
        if (h == 0) accm[r] = 0.25f * acc[r];
        else accm[r] += 0.25f * acc[r];
      }
    }
    __syncthreads();
  }

  if (mode != 2) {
    float* cb = out + (size_t)b * 4096;
#pragma unroll
    for (int r = 0; r < 16; ++r) {
      int i = wave * 16 + r;
      if (mode == 1) cb[i * 64 + lane] += accm[r];
      else cb[i * 64 + lane] = accm[r];
    }
  }
}

// ---------------- ai = [obs, comm] (B,N,192) ----------------
__global__ void build_ai_k(const float* __restrict__ obs, const float* __restrict__ comm,
                           float* __restrict__ ai) {
  size_t idx = (size_t)blockIdx.x * 256 + threadIdx.x;
  if (idx >= (size_t)NB * NAG * 192) return;
  int c = (int)(idx % 192);
  size_t bn = idx / 192;
  ai[idx] = (c < 128) ? obs[bn * 128 + c] : comm[bn * 64 + (c - 128)];
}

// ---------------- combined = [obs, actions] (B,N,144) ----------------
__global__ void build_combined_k(const float* __restrict__ obs, const float* __restrict__ act,
                                 float* __restrict__ cmb) {
  size_t idx = (size_t)blockIdx.x * 256 + threadIdx.x;
  if (idx >= (size_t)NB * NAG * 144) return;
  int c = (int)(idx % 144);
  size_t bn = idx / 144;
  cmb[idx] = (c < 128) ? obs[bn * 128 + c] : act[bn * 16 + (c - 128)];
}

// ---------------- split-K reduce + bias + relu for cent l1 ----------------
__global__ void reduce_bias_relu_k(const float* __restrict__ part, const float* __restrict__ bias,
                                   float* __restrict__ out) {
  int idx = blockIdx.x * 256 + threadIdx.x;
  float s = 0.f;
#pragma unroll
  for (int zz = 0; zz < 16; ++zz) s += part[(size_t)zz * 262144 + idx];
  s += bias[idx & 255];
  out[idx] = fmaxf(s, 0.f);
}

// ---------------- scm_pred = cw @ ce + noise ----------------
__global__ __launch_bounds__(256) void se_noise_k(const float* __restrict__ cw,
                                                  const float* __restrict__ ce,
                                                  const float* __restrict__ nz,
                                                  float* __restrict__ out) {
  int b = blockIdx.x;
  __shared__ float ceL[64 * 128];
  __shared__ float cwL[64 * 64];
  const float* cb = ce + (size_t)b * 8192;
  for (int idx = threadIdx.x; idx < 8192; idx += 256) ceL[idx] = cb[idx];
  for (int idx = threadIdx.x; idx < 4096; idx += 256) cwL[idx] = cw[idx];
  __syncthreads();
  for (int idx = threadIdx.x; idx < 8192; idx += 256) {
    int i = idx >> 7, d = idx & 127;
    float acc = 0.f;
    for (int j = 0; j < 64; ++j) acc += cwL[i * 64 + j] * ceL[j * 128 + d];
    out[(size_t)b * 8192 + idx] = acc + nz[(size_t)b * 8192 + idx];
  }
}

extern "C" void kernel_launch(void* const* d_in, const int* in_sizes, int n_in,
                              void* d_out, int out_size, void* d_ws, size_t ws_size,
                              hipStream_t stream) {
  (void)in_sizes; (void)n_in; (void)out_size; (void)ws_size;
  const float* obs = (const float*)d_in[0];
  const float* acts = (const float*)d_in[1];
  const float* adj = (const float*)d_in[2];
  const float* causal = (const float*)d_in[3];
  const float* gat_W = (const float*)d_in[4];
  const float* gat_a = (const float*)d_in[5];
  const float* cg_W0 = (const float*)d_in[6];
  const float* cg_a0 = (const float*)d_in[7];
  const float* cg_W1 = (const float*)d_in[8];
  const float* cg_a1 = (const float*)d_in[9];
  const float* aw1 = (const float*)d_in[10]; const float* ab1 = (const float*)d_in[11];
  const float* aw2 = (const float*)d_in[12]; const float* ab2 = (const float*)d_in[13];
  const float* aw3 = (const float*)d_in[14]; const float* ab3 = (const float*)d_in[15];
  const float* crw1 = (const float*)d_in[16]; const float* crb1 = (const float*)d_in[17];
  const float* crw2 = (const float*)d_in[18]; const float* crb2 = (const float*)d_in[19];
  const float* crw3 = (const float*)d_in[20]; const float* crb3 = (const float*)d_in[21];
  const float* cew1 = (const float*)d_in[22]; const float* ceb1 = (const float*)d_in[23];
  const float* cew2 = (const float*)d_in[24]; const float* ceb2 = (const float*)d_in[25];
  const float* cew3 = (const float*)d_in[26]; const float* ceb3 = (const float*)d_in[27];
  const float* scm_causal = (const float*)d_in[28];
  const float* mw1 = (const float*)d_in[29]; const float* mb1 = (const float*)d_in[30];
  const float* mw2 = (const float*)d_in[31]; const float* mb2 = (const float*)d_in[32];
  const float* mw3 = (const float*)d_in[33]; const float* mb3 = (const float*)d_in[34];
  const float* nw1 = (const float*)d_in[35]; const float* nb1 = (const float*)d_in[36];
  const float* nw2 = (const float*)d_in[37]; const float* nb2 = (const float*)d_in[38];

  // workspace layout (floats); total 65,515,520 floats = 249.9 MiB
  float* ws = (float*)d_ws;
  float* Ssm  = ws;               // 16384
  float* cwsm = ws + 16384;       // 4096
  float* comm = ws + 20480;       // 4,194,304  (B,N,64)
  float* AI   = ws + 4214784;     // 12,582,912 (B,N,192): ai -> combined -> ce
  float* H1   = ws + 16797696;    // 16,777,216 (B,N,256)
  float* HCG  = ws + 33574912;    // 16,777,216 (B,N,256)
  unsigned short* wbf = (unsigned short*)(ws + 50352128);  // bf16 weights
  unsigned short* SsmT  = wbf;             // 16384
  unsigned short* wcT   = wbf + 16384;     // 65536 (reused per GAT layer)
  unsigned short* aw1T  = wbf + 81920;     // 3,145,728
  unsigned short* aw2T  = wbf + 3227648;   // 4,194,304
  unsigned short* aw3T  = wbf + 7421952;   // 262,144
  unsigned short* crw1T = wbf + 7684096;   // 3,145,728
  unsigned short* crw2T = wbf + 10829824;  // 4,194,304
  unsigned short* crw3T = wbf + 15024128;  // 16,384
  unsigned short* cew1T = wbf + 15040512;  // 2,359,296
  unsigned short* cew2T = wbf + 17399808;  // 65,536
  unsigned short* cew3T = wbf + 17465344;  // 16,384
  unsigned short* mw1T  = wbf + 17481728;  // 2,359,296
  unsigned short* mw2T  = wbf + 19841024;  // 4,194,304
  unsigned short* mw3T  = wbf + 24035328;  // 2,097,152
  unsigned short* nw1T  = wbf + 26132480;  // 2,097,152
  unsigned short* nw2T  = wbf + 28229632;  // 2,097,152

  float* out_actor = (float*)d_out;
  float* out_critic = out_actor + 1048576;
  float* out_cent = out_critic + 65536;
  float* out_scm = out_cent + 65536;

  auto GEMM64 = [&](const float* A, const unsigned short* BT, const float* bias, float* C,
                    int M, int N, int K, long long lda, long long ldc,
                    long long aBS, long long btBS, long long biasBS, long long cBS,
                    int act, int gz, int kPerSplit) {
    dim3 grid(M / 64, (N + 63) / 64, gz);
    hipLaunchKernelGGL(gemm_mfma_k, grid, dim3(256), 0, stream, A, BT, bias, C, M, N, K,
                       lda, ldc, aBS, btBS, biasBS, cBS, act, kPerSplit);
  };
  auto GEMM128 = [&](const float* A, const unsigned short* BT, const float* bias, float* C,
                     int M, int N, int K, long long lda, long long ldc,
                     long long aBS, long long btBS, long long biasBS, long long cBS,
                     int act, int gz, int kPerSplit) {
    dim3 grid(M / 128, (N + 127) / 128, gz);
    hipLaunchKernelGGL(gemm_mfma128_k, grid, dim3(256), 0, stream, A, BT, bias, C, M, N, K,
                       lda, ldc, aBS, btBS, biasBS, cBS, act, kPerSplit);
  };
  auto TRN = [&](const float* in, unsigned short* out, int Z, int K, int N) {
    dim3 grid((K + 31) / 32, (N + 31) / 32, Z);
    hipLaunchKernelGGL(transpose_cvt_k, grid, dim3(32, 8), 0, stream, in, out, K, N);
  };

  // 0) small softmaxes + weight conversions (one-time per launch)
  hipLaunchKernelGGL(softmax_rows_k, dim3(128), dim3(64), 0, stream, causal, Ssm, 128);
  hipLaunchKernelGGL(softmax_rows_k, dim3(64), dim3(64), 0, stream, scm_causal, cwsm, 64);
  TRN(Ssm, SsmT, 1, 128, 128);
  TRN(aw1, aw1T, 64, 192, 256);  TRN(aw2, aw2T, 64, 256, 256);  TRN(aw3, aw3T, 64, 256, 16);
  TRN(crw1, crw1T, 64, 192, 256); TRN(crw2, crw2T, 64, 256, 256); TRN(crw3, crw3T, 64, 256, 1);
  TRN(cew1, cew1T, 1, 9216, 256); TRN(cew2, cew2T, 1, 256, 256);  TRN(cew3, cew3T, 1, 256, 64);
  TRN(mw1, mw1T, 64, 144, 256);  TRN(mw2, mw2T, 64, 256, 256);  TRN(mw3, mw3T, 64, 256, 128);
  TRN(nw1, nw1T, 64, 128, 256);  TRN(nw2, nw2T, 64, 256, 128);

  // 1) plain GAT -> comm (init)
  hipLaunchKernelGGL(repack_wT_k, dim3((NH * 128 * 64 + 255) / 256), dim3(256), 0, stream, gat_W, wcT, 128);
  GEMM128(obs, wcT, nullptr, H1, 65536, 256, 128, 128, 256, 0, 0, 0, 0, 0, 1, 0);     // xt1
  hipLaunchKernelGGL(gat_attn4_k, dim3(1024), dim3(256), 0, stream, H1, gat_a, adj, comm, 0);

  // 2) causal GAT
  GEMM128(obs, SsmT, nullptr, HCG, 65536, 128, 128, 128, 128, 0, 0, 0, 0, 0, 1, 0);   // xm
  hipLaunchKernelGGL(repack_wT_k, dim3((NH * 128 * 64 + 255) / 256), dim3(256), 0, stream, cg_W0, wcT, 128);
  GEMM128(HCG, wcT, nullptr, H1, 65536, 256, 128, 128, 256, 0, 0, 0, 0, 0, 1, 0);     // xt_cg0
  hipLaunchKernelGGL(gat_attn4_k, dim3(1024), dim3(256), 0, stream, H1, cg_a0, adj, HCG, 2); // hcg (ELU)
  hipLaunchKernelGGL(repack_wT_k, dim3((NH * 256 * 64 + 255) / 256), dim3(256), 0, stream, cg_W1, wcT, 256);
  GEMM128(HCG, wcT, nullptr, H1, 65536, 256, 256, 256, 256, 0, 0, 0, 0, 0, 1, 0);     // xt_cg1
  hipLaunchKernelGGL(gat_attn4_k, dim3(1024), dim3(256), 0, stream, H1, cg_a1, adj, comm, 1);

  // 3) ai = [obs, comm]
  hipLaunchKernelGGL(build_ai_k, dim3((12582912 + 255) / 256), dim3(256), 0, stream, obs, comm, AI);

  // 4) actor MLP (per-agent)
  GEMM128(AI, aw1T, ab1, H1, 1024, 256, 192, 12288, 16384, 192, 49152, 256, 256, 1, 64, 0);
  GEMM128(H1, aw2T, ab2, HCG, 1024, 256, 256, 16384, 16384, 256, 65536, 256, 256, 1, 64, 0);
  GEMM64(HCG, aw3T, ab3, out_actor, 1024, 16, 256, 16384, 1024, 256, 4096, 16, 16, 0, 64, 0);

  // 5) critic MLP (per-agent)
  GEMM128(AI, crw1T, crb1, H1, 1024, 256, 192, 12288, 16384, 192, 49152, 256, 256, 1, 64, 0);
  GEMM128(H1, crw2T, crb2, HCG, 1024, 256, 256, 16384, 16384, 256, 65536, 256, 256, 1, 64, 0);
  GEMM64(HCG, crw3T, crb3, out_critic, 1024, 1, 256, 16384, 64, 256, 256, 1, 1, 0, 64, 0);

  // 6) centralized critic (combined -> AI)
  hipLaunchKernelGGL(build_combined_k, dim3((9437184 + 255) / 256), dim3(256), 0, stream, obs, acts, AI);
  GEMM128(AI, cew1T, nullptr, H1, 1024, 256, 9216, 9216, 256, 0, 0, 0, 262144, 0, 16, 576);
  hipLaunchKernelGGL(reduce_bias_relu_k, dim3(1024), dim3(256), 0, stream, H1, ceb1, HCG);
  GEMM64(HCG, cew2T, ceb2, H1, 1024, 256, 256, 256, 256, 0, 0, 0, 0, 1, 1, 0);
  GEMM64(H1, cew3T, ceb3, out_cent, 1024, 64, 256, 256, 64, 0, 0, 0, 0, 0, 1, 0);

  // 7) SCM mechanisms (input = combined in AI)
  GEMM128(AI, mw1T, mb1, H1, 1024, 256, 144, 9216, 16384, 144, 36864, 256, 256, 1, 64, 0);
  GEMM128(H1, mw2T, mb2, HCG, 1024, 256, 256, 16384, 16384, 256, 65536, 256, 256, 1, 64, 0);
  GEMM128(HCG, mw3T, mb3, AI, 1024, 128, 256, 16384, 8192, 256, 32768, 128, 128, 0, 64, 0); // ce -> AI

  // 8) noise model (input = obs)
  GEMM128(obs, nw1T, nb1, H1, 1024, 256, 128, 8192, 16384, 128, 32768, 256, 256, 1, 64, 0);
  GEMM128(H1, nw2T, nb2, HCG, 1024, 128, 256, 16384, 8192, 256, 32768, 128, 128, 0, 64, 0); // noise -> HCG

  // 9) scm_pred = softmax(scm_causal) @ ce + noise
  hipLaunchKernelGGL(se_noise_k, dim3(1024), dim3(256), 0, stream, cwsm, AI, HCG, out_scm);
}